// Round 1
// baseline (585.002 us; speedup 1.0000x reference)
//
#include <hip/hip_runtime.h>
#include <math.h>

#define N_N 20000
#define N_E 160000
#define KK 2112   // 2048 (P) + 32 (xsum for b2) + 32 (x*cnt for root_w)

// ---------------- edge MLP layer 1: he[e,k] = relu(ea[e]·w1[k] + b1[k]) ----------------
__global__ __launch_bounds__(256) void k_mlp1(const float* __restrict__ ea,
    const float* __restrict__ w1, const float* __restrict__ b1,
    float* __restrict__ he) {
  int t = threadIdx.x;
  int e = blockIdx.x * 4 + (t >> 6);
  int j = t & 63;
  const float* a = ea + (size_t)e * 16;
  const float* wr = w1 + j * 16;
  float s = b1[j];
#pragma unroll
  for (int i = 0; i < 16; ++i) s += a[i] * wr[i];
  he[(size_t)e * 64 + j] = fmaxf(s, 0.f);
}

// ---------------- CSR build by dst ----------------
__global__ __launch_bounds__(256) void k_hist(const int* __restrict__ eidx,
    int* __restrict__ cnt) {
  int e = blockIdx.x * 256 + threadIdx.x;
  atomicAdd(&cnt[eidx[N_E + e]], 1);
}

__global__ __launch_bounds__(1024) void k_scan(const int* __restrict__ hist,
    int* __restrict__ starts) {
  __shared__ int part[1024];
  int t = threadIdx.x;
  const int CH = 20;                    // 1024*20 >= 20000
  int lo = t * CH;
  int hi = lo + CH; if (hi > N_N) hi = N_N;
  int s = 0;
  for (int i = lo; i < hi; ++i) s += hist[i];
  part[t] = s;
  __syncthreads();
  for (int off = 1; off < 1024; off <<= 1) {
    int v = (t >= off) ? part[t - off] : 0;
    __syncthreads();
    part[t] += v;
    __syncthreads();
  }
  int run = (t == 0) ? 0 : part[t - 1];
  for (int i = lo; i < hi; ++i) { starts[i] = run; run += hist[i]; }
  if (t == 1023) starts[N_N] = part[1023];
}

__global__ __launch_bounds__(256) void k_scatter(const int* __restrict__ eidx,
    const int* __restrict__ starts, int* __restrict__ cur,
    int* __restrict__ elist) {
  int e = blockIdx.x * 256 + threadIdx.x;
  int dn = eidx[N_E + e];
  int pos = atomicAdd(&cur[dn], 1);
  elist[starts[dn] + pos] = e;
}

// ---------------- build B matrix [2112][64] for the fused GEMM ----------------
// rows 0..2047  (d*64+k): W[d,h,k] = en_w2[(d*64+h)*64+k]
// rows 2048..2079 (d)   : B2[d,h]  = en_b2[d*64+h]        (multiplies xsum, inside mean)
// rows 2080..2111 (d)   : root_w[d,h]                      (multiplies x*cnt -> cancels mean)
__global__ __launch_bounds__(256) void k_bt(const float* __restrict__ w2,
    const float* __restrict__ b2, const float* __restrict__ rootw,
    float* __restrict__ Bt) {
  int idx = blockIdx.x * 256 + threadIdx.x;   // 0..135167
  int row = idx >> 6, h = idx & 63;
  float v;
  if (row < 2048) { int d = row >> 6, k = row & 63; v = w2[((d << 6) + h) * 64 + k]; }
  else if (row < 2080) { int d = row - 2048; v = b2[(d << 6) + h]; }
  else { int d = row - 2080; v = rootw[(d << 6) + h]; }
  Bt[idx] = v;
}

// ---------------- per-node P accumulation (outer products over in-edges) ----------------
__global__ __launch_bounds__(256) void k_pbuild(const float* __restrict__ x,
    const int* __restrict__ eidx, const float* __restrict__ he,
    const int* __restrict__ starts, const int* __restrict__ elist,
    float* __restrict__ A) {
  int n = blockIdx.x;
  int tid = threadIdx.x;
  int d = tid >> 3;                 // 0..31
  int kq = (tid & 7) * 2;           // float4 index into he row
  int s0 = starts[n], s1 = starts[n + 1];
  float4 acc0 = {0.f, 0.f, 0.f, 0.f}, acc1 = {0.f, 0.f, 0.f, 0.f};
  float xs = 0.f;
  for (int i = s0; i < s1; ++i) {
    int e = elist[i];
    int src = eidx[e];
    float xv = x[src * 32 + d];
    const float4* hp = (const float4*)(he + (size_t)e * 64);
    float4 h0 = hp[kq], h1 = hp[kq + 1];
    acc0.x += xv * h0.x; acc0.y += xv * h0.y; acc0.z += xv * h0.z; acc0.w += xv * h0.w;
    acc1.x += xv * h1.x; acc1.y += xv * h1.y; acc1.z += xv * h1.z; acc1.w += xv * h1.w;
    if (tid < 32) xs += x[src * 32 + tid];
  }
  float* Arow = A + (size_t)n * KK;
  ((float4*)Arow)[tid * 2] = acc0;
  ((float4*)Arow)[tid * 2 + 1] = acc1;
  if (tid < 32) {
    Arow[2048 + tid] = xs;
    int cnt = s1 - s0; if (cnt < 1) cnt = 1;
    Arow[2080 + tid] = x[n * 32 + tid] * (float)cnt;
  }
}

// ---------------- GEMM [N,2112]x[2112,64] with mean + conv_b + relu epilogue ----------------
__global__ __launch_bounds__(256) void k_gemm(const float* __restrict__ A,
    const float* __restrict__ B, const int* __restrict__ starts,
    const float* __restrict__ convb, float* __restrict__ xh) {
  __shared__ float As[64][33];
  __shared__ float Bs[32][68];
  int tid = threadIdx.x;
  int tr = tid >> 4, tc = tid & 15;
  int row0 = blockIdx.x * 64;
  float acc[4][4] = {{0.f}};
  for (int k0 = 0; k0 < KK; k0 += 32) {
#pragma unroll
    for (int l = 0; l < 8; ++l) {
      int idx = tid + l * 256;
      int m = idx >> 5, k = idx & 31;
      int n = row0 + m;
      As[m][k] = (n < N_N) ? A[(size_t)n * KK + k0 + k] : 0.f;
      int kb = idx >> 6, h = idx & 63;
      Bs[kb][h] = B[(k0 + kb) * 64 + h];
    }
    __syncthreads();
#pragma unroll
    for (int k = 0; k < 32; ++k) {
      float a0 = As[tr * 4 + 0][k];
      float a1 = As[tr * 4 + 1][k];
      float a2 = As[tr * 4 + 2][k];
      float a3 = As[tr * 4 + 3][k];
      float4 b = *(const float4*)&Bs[k][tc * 4];
      acc[0][0] += a0 * b.x; acc[0][1] += a0 * b.y; acc[0][2] += a0 * b.z; acc[0][3] += a0 * b.w;
      acc[1][0] += a1 * b.x; acc[1][1] += a1 * b.y; acc[1][2] += a1 * b.z; acc[1][3] += a1 * b.w;
      acc[2][0] += a2 * b.x; acc[2][1] += a2 * b.y; acc[2][2] += a2 * b.z; acc[2][3] += a2 * b.w;
      acc[3][0] += a3 * b.x; acc[3][1] += a3 * b.y; acc[3][2] += a3 * b.z; acc[3][3] += a3 * b.w;
    }
    __syncthreads();
  }
#pragma unroll
  for (int i = 0; i < 4; ++i) {
    int n = row0 + tr * 4 + i;
    if (n < N_N) {
      int cnt = starts[n + 1] - starts[n]; if (cnt < 1) cnt = 1;
      float inv = 1.f / (float)cnt;
      float4 o;
      o.x = fmaxf(acc[i][0] * inv + convb[tc * 4 + 0], 0.f);
      o.y = fmaxf(acc[i][1] * inv + convb[tc * 4 + 1], 0.f);
      o.z = fmaxf(acc[i][2] * inv + convb[tc * 4 + 2], 0.f);
      o.w = fmaxf(acc[i][3] * inv + convb[tc * 4 + 3], 0.f);
      *(float4*)&xh[(size_t)n * 64 + tc * 4] = o;
    }
  }
}

// ---------------- QKV projection, scattered to [G][NH][200][16] layouts ----------------
__global__ __launch_bounds__(256) void k_qkv(const float* __restrict__ xh,
    const float* __restrict__ w, const float* __restrict__ b,
    float* __restrict__ Qb, float* __restrict__ Kb, float* __restrict__ Vb) {
  __shared__ float Ws[192 * 65];
  __shared__ float xs[8 * 64];
  int t = threadIdx.x;
  int n0 = blockIdx.x * 8;
  for (int idx = t; idx < 192 * 64; idx += 256)
    Ws[(idx >> 6) * 65 + (idx & 63)] = w[idx];
  for (int idx = t; idx < 8 * 64; idx += 256)
    xs[idx] = xh[(size_t)n0 * 64 + idx];
  __syncthreads();
  int i = t >> 5, l5 = t & 31;
  int n = n0 + i, g = n / 200, p = n % 200;
#pragma unroll
  for (int q = 0; q < 6; ++q) {
    int j = l5 + 32 * q;
    float acc = b[j];
#pragma unroll
    for (int k = 0; k < 64; ++k) acc += Ws[j * 65 + k] * xs[i * 64 + k];
    int part = j >> 6, rem = j & 63, hh = rem >> 4, dd = rem & 15;
    float* dst = (part == 0) ? Qb : (part == 1 ? Kb : Vb);
    dst[(((size_t)g * 4 + hh) * 200 + p) * 16 + dd] = acc;
  }
}

// ---------------- attention: one block per (graph, head) ----------------
__global__ __launch_bounds__(256) void k_attn(const float* __restrict__ Qb,
    const float* __restrict__ Kb, const float* __restrict__ Vb,
    float* __restrict__ ctx) {
  __shared__ float Qs[200 * 16];
  __shared__ float Ks[200 * 17];
  __shared__ float Vs[200 * 17];
  int t = threadIdx.x;
  size_t base = (size_t)blockIdx.x * 200 * 16;
  for (int idx = t; idx < 3200; idx += 256) {
    int p = idx >> 4, d2 = idx & 15;
    Qs[idx] = Qb[base + idx];
    Ks[p * 17 + d2] = Kb[base + idx];
    Vs[p * 17 + d2] = Vb[base + idx];
  }
  __syncthreads();
  int wave = t >> 6, lane = t & 63;
  int dd = lane >> 2, r = lane & 3;
  for (int p = wave; p < 200; p += 4) {
    float ql[16];
#pragma unroll
    for (int i2 = 0; i2 < 16; ++i2) ql[i2] = Qs[p * 16 + i2];
    float sc[4];
#pragma unroll
    for (int t2 = 0; t2 < 4; ++t2) {
      int j = lane + 64 * t2;
      if (j < 200) {
        float s = 0.f;
#pragma unroll
        for (int i2 = 0; i2 < 16; ++i2) s += ql[i2] * Ks[j * 17 + i2];
        sc[t2] = s * 0.25f;          // 1/sqrt(16)
      } else sc[t2] = -INFINITY;
    }
    float m = fmaxf(fmaxf(sc[0], sc[1]), fmaxf(sc[2], sc[3]));
#pragma unroll
    for (int off = 32; off >= 1; off >>= 1) m = fmaxf(m, __shfl_xor(m, off));
    float ev[4], lsum = 0.f;
#pragma unroll
    for (int t2 = 0; t2 < 4; ++t2) { ev[t2] = __expf(sc[t2] - m); lsum += ev[t2]; }
#pragma unroll
    for (int off = 32; off >= 1; off >>= 1) lsum += __shfl_xor(lsum, off);
    float inv = 1.f / lsum;
    float acc = 0.f;
#pragma unroll
    for (int b2 = 0; b2 < 4; ++b2) {
#pragma unroll
      for (int ii = 0; ii < 16; ++ii) {
        int i2 = b2 * 16 + ii;
        if (i2 >= 50) break;        // compile-time under full unroll
        int j = r + 4 * i2;         // < 200 always
        float pj = __shfl(ev[b2], j & 63);
        acc += pj * Vs[j * 17 + dd];
      }
    }
    acc += __shfl_xor(acc, 1);
    acc += __shfl_xor(acc, 2);
    if (r == 0) ctx[base + p * 16 + dd] = acc * inv;
  }
}

// ---------------- pool (linearity: pool ctx before out_proj) + MLP head ----------------
__global__ __launch_bounds__(64) void k_head(const float* __restrict__ ctx,
    const float* __restrict__ ow, const float* __restrict__ ob,
    const float* __restrict__ w1, const float* __restrict__ b1,
    const float* __restrict__ w2, const float* __restrict__ b2,
    float* __restrict__ out) {
  __shared__ float ms[64], es[64];
  int g = blockIdx.x, t = threadIdx.x;
  int hh = t >> 4, dd = t & 15;
  const float* cb = ctx + (((size_t)g * 4 + hh) * 200) * 16 + dd;
  float s = 0.f;
  for (int p = 0; p < 200; ++p) s += cb[p * 16];
  ms[t] = s * (1.f / 200.f);
  __syncthreads();
  float e = ob[t];
  for (int j = 0; j < 64; ++j) e += ow[t * 64 + j] * ms[j];
  es[t] = e;
  __syncthreads();
  float h1 = b1[t];
  for (int j = 0; j < 64; ++j) h1 += w1[t * 64 + j] * es[j];
  h1 = fmaxf(h1, 0.f);
  float pr = h1 * w2[t];
  for (int off = 32; off >= 1; off >>= 1) pr += __shfl_xor(pr, off);
  if (t == 0) out[g] = pr + b2[0];
}

extern "C" void kernel_launch(void* const* d_in, const int* in_sizes, int n_in,
                              void* d_out, int out_size, void* d_ws, size_t ws_size,
                              hipStream_t stream) {
  (void)in_sizes; (void)n_in;
  const float* x      = (const float*)d_in[0];
  const int*   eidx   = (const int*)d_in[1];
  const float* ea     = (const float*)d_in[2];
  /* d_in[3] = batch: structure is n/200 by construction */
  const float* en_w1  = (const float*)d_in[4];
  const float* en_b1  = (const float*)d_in[5];
  const float* en_w2  = (const float*)d_in[6];
  const float* en_b2  = (const float*)d_in[7];
  const float* root_w = (const float*)d_in[8];
  const float* conv_b = (const float*)d_in[9];
  const float* in_w   = (const float*)d_in[10];
  const float* in_b   = (const float*)d_in[11];
  const float* out_w  = (const float*)d_in[12];
  const float* out_b  = (const float*)d_in[13];
  const float* l1w    = (const float*)d_in[14];
  const float* l1b    = (const float*)d_in[15];
  const float* l2w    = (const float*)d_in[16];
  const float* l2b    = (const float*)d_in[17];
  float* out = (float*)d_out;

  // workspace layout (bytes)
  char* w = (char*)d_ws;
  const size_t szA  = (size_t)N_N * KK * 4;       // 168,960,000
  const size_t szHE = (size_t)N_E * 64 * 4;       //  40,960,000
  float* A   = (float*)w;
  char* r2   = w + szA;
  float* he  = (float*)r2;                        // alive K1 -> K_pbuild
  float* xh  = (float*)r2;                        // alive K_gemm -> k_qkv (he dead)
  float* Qb  = (float*)(r2 + 5120000);
  float* Kb  = (float*)(r2 + 10240000);
  float* Vb  = (float*)(r2 + 15360000);
  float* ctx = (float*)(r2 + 20480000);
  char* r3   = r2 + szHE;
  float* Bt  = (float*)r3;                        // 2112*64*4 = 540,672
  int* starts = (int*)(r3 + 540672);              // N+1 ints (+pad)
  int* elist  = starts + (N_N + 4);
  int* cursor = elist + N_E;
  size_t need = szA + szHE + 540672 + (size_t)(N_N + 4) * 4 + (size_t)N_E * 4 + (size_t)N_N * 4;
  if (ws_size < need || out_size < 100) return;

  hipMemsetAsync(cursor, 0, N_N * 4, stream);
  k_mlp1<<<N_E / 4, 256, 0, stream>>>(ea, en_w1, en_b1, he);
  k_hist<<<N_E / 256, 256, 0, stream>>>(eidx, cursor);
  k_scan<<<1, 1024, 0, stream>>>(cursor, starts);
  hipMemsetAsync(cursor, 0, N_N * 4, stream);
  k_scatter<<<N_E / 256, 256, 0, stream>>>(eidx, starts, cursor, elist);
  k_bt<<<(2112 * 64) / 256, 256, 0, stream>>>(en_w2, en_b2, root_w, Bt);
  k_pbuild<<<N_N, 256, 0, stream>>>(x, eidx, he, starts, elist, A);
  k_gemm<<<(N_N + 63) / 64, 256, 0, stream>>>(A, Bt, starts, conv_b, xh);
  k_qkv<<<N_N / 8, 256, 0, stream>>>(xh, in_w, in_b, Qb, Kb, Vb);
  k_attn<<<400, 256, 0, stream>>>(Qb, Kb, Vb, ctx);
  k_head<<<100, 64, 0, stream>>>(ctx, out_w, out_b, l1w, l1b, l2w, l2b, out);
}

// Round 2
// 334.697 us; speedup vs baseline: 1.7479x; 1.7479x over previous
//
#include <hip/hip_runtime.h>
#include <math.h>

#define N_N 20000
#define N_E 160000
// A matrix columns: 2048 (P) + 32 (xsum for b2) + 32 (x*cnt for root_w) = 2112 = 66*32
#define NKB 66

typedef __attribute__((ext_vector_type(8))) short bfrag;
typedef __attribute__((ext_vector_type(4))) float facc;

__device__ __forceinline__ unsigned short f2bf(float f) {
  union { float f; unsigned u; } v; v.f = f;
  unsigned u = v.u;
  return (unsigned short)((u + 0x7FFF + ((u >> 16) & 1)) >> 16);
}

// ---------------- edge MLP layer 1: he[e,k] = relu(ea[e]·w1[k] + b1[k]) ----------------
__global__ __launch_bounds__(256) void k_mlp1(const float* __restrict__ ea,
    const float* __restrict__ w1, const float* __restrict__ b1,
    float* __restrict__ he) {
  int t = threadIdx.x;
  int e = blockIdx.x * 4 + (t >> 6);
  int j = t & 63;
  const float* a = ea + (size_t)e * 16;
  const float* wr = w1 + j * 16;
  float s = b1[j];
#pragma unroll
  for (int i = 0; i < 16; ++i) s += a[i] * wr[i];
  he[(size_t)e * 64 + j] = fmaxf(s, 0.f);
}

// ---------------- CSR build by dst ----------------
__global__ __launch_bounds__(256) void k_hist(const int* __restrict__ eidx,
    int* __restrict__ cnt) {
  int e = blockIdx.x * 256 + threadIdx.x;
  atomicAdd(&cnt[eidx[N_E + e]], 1);
}

__global__ __launch_bounds__(1024) void k_scan(const int* __restrict__ hist,
    int* __restrict__ starts) {
  __shared__ int part[1024];
  int t = threadIdx.x;
  const int CH = 20;
  int lo = t * CH;
  int hi = lo + CH; if (hi > N_N) hi = N_N;
  int s = 0;
  for (int i = lo; i < hi; ++i) s += hist[i];
  part[t] = s;
  __syncthreads();
  for (int off = 1; off < 1024; off <<= 1) {
    int v = (t >= off) ? part[t - off] : 0;
    __syncthreads();
    part[t] += v;
    __syncthreads();
  }
  int run = (t == 0) ? 0 : part[t - 1];
  for (int i = lo; i < hi; ++i) { starts[i] = run; run += hist[i]; }
  if (t == 1023) starts[N_N] = part[1023];
}

__global__ __launch_bounds__(256) void k_scatter(const int* __restrict__ eidx,
    const int* __restrict__ starts, int* __restrict__ cur,
    int* __restrict__ elist) {
  int e = blockIdx.x * 256 + threadIdx.x;
  int dn = eidx[N_E + e];
  int pos = atomicAdd(&cur[dn], 1);
  elist[starts[dn] + pos] = e;
}

// ---------------- B matrix [2112][64] packed into MFMA B-fragment layout (bf16) ----------
// Bp[((kb*4+cb)*64 + l)*8 + i] = B[kb*32 + (l>>4)*8 + i][cb*16 + (l&15)]
// B rows 0..2047 (d*64+k): en_w2[(d*64+c)*64+k]; 2048..2079: b2[d*64+c]; 2080..2111: rootw
__global__ __launch_bounds__(256) void k_bt(const float* __restrict__ w2,
    const float* __restrict__ b2f, const float* __restrict__ rootw,
    unsigned short* __restrict__ Bp) {
  int idx = blockIdx.x * 256 + threadIdx.x;     // < 135168
  int i = idx & 7, l = (idx >> 3) & 63, cbkb = idx >> 9;
  int cb = cbkb & 3, kb = cbkb >> 2;
  int r = kb * 32 + ((l >> 4) << 3) + i;
  int c = (cb << 4) + (l & 15);
  float v;
  if (r < 2048) { int d = r >> 6, k = r & 63; v = w2[((d << 6) + c) * 64 + k]; }
  else if (r < 2080) v = b2f[((r - 2048) << 6) + c];
  else v = rootw[((r - 2080) << 6) + c];
  Bp[idx] = f2bf(v);
}

// ---------------- in_proj W packed for QKV MFMA: B2[((kb*12+cb)*64+l)*8+i] ----------------
__global__ __launch_bounds__(256) void k_bt2(const float* __restrict__ inw,
    unsigned short* __restrict__ B2p) {
  int idx = blockIdx.x * 256 + threadIdx.x;     // < 12288
  int i = idx & 7, l = (idx >> 3) & 63, cbkb = idx >> 9;   // 0..23
  int cb = cbkb % 12, kb = cbkb / 12;
  int r = kb * 32 + ((l >> 4) << 3) + i;        // 0..63 (input dim)
  int c = (cb << 4) + (l & 15);                 // 0..191 (output)
  B2p[idx] = f2bf(inw[c * 64 + r]);
}

// ---------------- per-node P accumulation -> bf16 A in MFMA A-fragment layout -------------
// Ap[((r0*66 + kb)*64 + (m + 16*b))*8 + i] = A[n = r0*16+m][c = kb*32 + b*8 + i]
__global__ __launch_bounds__(256) void k_pbuild(const float* __restrict__ x,
    const int* __restrict__ eidx, const float* __restrict__ he,
    const int* __restrict__ starts, const int* __restrict__ elist,
    unsigned short* __restrict__ Ap) {
  int n = blockIdx.x;
  int tid = threadIdx.x;
  int d = tid >> 3;                 // 0..31
  int j8 = tid & 7;                 // owns he k-range j8*8..j8*8+7
  int s0 = starts[n], s1 = starts[n + 1];
  float4 acc0 = {0.f, 0.f, 0.f, 0.f}, acc1 = {0.f, 0.f, 0.f, 0.f};
  float xs = 0.f;
  for (int i = s0; i < s1; ++i) {
    int e = elist[i];
    int src = eidx[e];
    float xv = x[src * 32 + d];
    const float4* hp = (const float4*)(he + (size_t)e * 64);
    float4 h0 = hp[j8 * 2], h1 = hp[j8 * 2 + 1];
    acc0.x += xv * h0.x; acc0.y += xv * h0.y; acc0.z += xv * h0.z; acc0.w += xv * h0.w;
    acc1.x += xv * h1.x; acc1.y += xv * h1.y; acc1.z += xv * h1.z; acc1.w += xv * h1.w;
    if (tid < 32) xs += x[src * 32 + tid];
  }
  int r0 = n >> 4, m = n & 15;
  int kb = 2 * d + (j8 >> 2), b = j8 & 3;
  uint4 pk;
  pk.x = (unsigned)f2bf(acc0.x) | ((unsigned)f2bf(acc0.y) << 16);
  pk.y = (unsigned)f2bf(acc0.z) | ((unsigned)f2bf(acc0.w) << 16);
  pk.z = (unsigned)f2bf(acc1.x) | ((unsigned)f2bf(acc1.y) << 16);
  pk.w = (unsigned)f2bf(acc1.z) | ((unsigned)f2bf(acc1.w) << 16);
  *(uint4*)(Ap + ((size_t)(r0 * NKB + kb) * 64 + m + 16 * b) * 8) = pk;
  if (tid < 32) {
    int cnt = s1 - s0; if (cnt < 1) cnt = 1;
    Ap[((size_t)(r0 * NKB + 64) * 64 + m + 16 * (tid >> 3)) * 8 + (tid & 7)] = f2bf(xs);
    Ap[((size_t)(r0 * NKB + 65) * 64 + m + 16 * (tid >> 3)) * 8 + (tid & 7)] =
        f2bf(x[n * 32 + tid] * (float)cnt);
  }
}

// ---------------- MFMA GEMM [N,2112]x[2112,64] + mean + conv_b + relu ->
// ---------------- xh written as bf16 A-fragments (A2) for the QKV GEMM ----------------
__global__ __launch_bounds__(64) void k_gemm_mfma(const unsigned short* __restrict__ Ap,
    const unsigned short* __restrict__ Bp, const int* __restrict__ starts,
    const float* __restrict__ convb, unsigned short* __restrict__ A2) {
  int l = threadIdx.x;
  int r0 = blockIdx.x;                       // 0..1249
  const bfrag* Arow = (const bfrag*)Ap + (size_t)r0 * NKB * 64 + l;
  const bfrag* Bb = (const bfrag*)Bp + l;
  facc acc0 = {0.f, 0.f, 0.f, 0.f};
  facc acc1 = {0.f, 0.f, 0.f, 0.f};
  facc acc2 = {0.f, 0.f, 0.f, 0.f};
  facc acc3 = {0.f, 0.f, 0.f, 0.f};
#pragma unroll 2
  for (int kb = 0; kb < NKB; ++kb) {
    bfrag af = Arow[kb * 64];
    const bfrag* bp = Bb + kb * 256;
    acc0 = __builtin_amdgcn_mfma_f32_16x16x32_bf16(af, bp[0],   acc0, 0, 0, 0);
    acc1 = __builtin_amdgcn_mfma_f32_16x16x32_bf16(af, bp[64],  acc1, 0, 0, 0);
    acc2 = __builtin_amdgcn_mfma_f32_16x16x32_bf16(af, bp[128], acc2, 0, 0, 0);
    acc3 = __builtin_amdgcn_mfma_f32_16x16x32_bf16(af, bp[192], acc3, 0, 0, 0);
  }
  int col = l & 15;
  float cv0 = convb[col], cv1 = convb[16 + col], cv2 = convb[32 + col], cv3 = convb[48 + col];
#pragma unroll
  for (int j = 0; j < 4; ++j) {
    int m = ((l >> 4) << 2) + j;
    int n = r0 * 16 + m;
    int cnt = starts[n + 1] - starts[n]; if (cnt < 1) cnt = 1;
    float inv = 1.f / (float)cnt;
    float v[4];
    v[0] = fmaxf(acc0[j] * inv + cv0, 0.f);
    v[1] = fmaxf(acc1[j] * inv + cv1, 0.f);
    v[2] = fmaxf(acc2[j] * inv + cv2, 0.f);
    v[3] = fmaxf(acc3[j] * inv + cv3, 0.f);
#pragma unroll
    for (int q = 0; q < 4; ++q) {
      int c = q * 16 + col;
      int kb2 = c >> 5, b = (c >> 3) & 3, i = c & 7;
      A2[((size_t)(r0 * 2 + kb2) * 64 + m + 16 * b) * 8 + i] = f2bf(v[q]);
    }
  }
}

// ---------------- QKV MFMA GEMM [N,64]x[64,192], scatter to [G][NH][200][16] --------------
__global__ __launch_bounds__(64) void k_qkv_mfma(const unsigned short* __restrict__ A2,
    const unsigned short* __restrict__ B2p, const float* __restrict__ inb,
    float* __restrict__ Qb, float* __restrict__ Kb, float* __restrict__ Vb) {
  int l = threadIdx.x;
  int r0 = blockIdx.x;
  const bfrag* A2r = (const bfrag*)A2 + (size_t)r0 * 128 + l;
  const bfrag* B2b = (const bfrag*)B2p + l;
  facc acc[12];
#pragma unroll
  for (int cb = 0; cb < 12; ++cb) { facc z = {0.f, 0.f, 0.f, 0.f}; acc[cb] = z; }
#pragma unroll
  for (int kb = 0; kb < 2; ++kb) {
    bfrag af = A2r[kb * 64];
#pragma unroll
    for (int cb = 0; cb < 12; ++cb)
      acc[cb] = __builtin_amdgcn_mfma_f32_16x16x32_bf16(af, B2b[(kb * 12 + cb) * 64], acc[cb], 0, 0, 0);
  }
  int col = l & 15;
#pragma unroll
  for (int j = 0; j < 4; ++j) {
    int n = r0 * 16 + ((l >> 4) << 2) + j;
    int g = n / 200, p = n - g * 200;
#pragma unroll
    for (int cb = 0; cb < 12; ++cb) {
      int c = cb * 16 + col;
      float v = acc[cb][j] + inb[c];
      int part = c >> 6, rem = c & 63, hh = rem >> 4, dd = rem & 15;
      float* dst = (part == 0) ? Qb : (part == 1 ? Kb : Vb);
      dst[(((size_t)g * 4 + hh) * 200 + p) * 16 + dd] = v;
    }
  }
}

// ---------------- attention: one block per (graph, head) ----------------
__global__ __launch_bounds__(256) void k_attn(const float* __restrict__ Qb,
    const float* __restrict__ Kb, const float* __restrict__ Vb,
    float* __restrict__ ctx) {
  __shared__ float Qs[200 * 16];
  __shared__ float Ks[200 * 17];
  __shared__ float Vs[200 * 17];
  int t = threadIdx.x;
  size_t base = (size_t)blockIdx.x * 200 * 16;
  for (int idx = t; idx < 3200; idx += 256) {
    int p = idx >> 4, d2 = idx & 15;
    Qs[idx] = Qb[base + idx];
    Ks[p * 17 + d2] = Kb[base + idx];
    Vs[p * 17 + d2] = Vb[base + idx];
  }
  __syncthreads();
  int wave = t >> 6, lane = t & 63;
  int dd = lane >> 2, r = lane & 3;
  for (int p = wave; p < 200; p += 4) {
    float ql[16];
#pragma unroll
    for (int i2 = 0; i2 < 16; ++i2) ql[i2] = Qs[p * 16 + i2];
    float sc[4];
#pragma unroll
    for (int t2 = 0; t2 < 4; ++t2) {
      int j = lane + 64 * t2;
      if (j < 200) {
        float s = 0.f;
#pragma unroll
        for (int i2 = 0; i2 < 16; ++i2) s += ql[i2] * Ks[j * 17 + i2];
        sc[t2] = s * 0.25f;
      } else sc[t2] = -INFINITY;
    }
    float m = fmaxf(fmaxf(sc[0], sc[1]), fmaxf(sc[2], sc[3]));
#pragma unroll
    for (int off = 32; off >= 1; off >>= 1) m = fmaxf(m, __shfl_xor(m, off));
    float ev[4], lsum = 0.f;
#pragma unroll
    for (int t2 = 0; t2 < 4; ++t2) { ev[t2] = __expf(sc[t2] - m); lsum += ev[t2]; }
#pragma unroll
    for (int off = 32; off >= 1; off >>= 1) lsum += __shfl_xor(lsum, off);
    float inv = 1.f / lsum;
    float acc = 0.f;
#pragma unroll
    for (int b2 = 0; b2 < 4; ++b2) {
#pragma unroll
      for (int ii = 0; ii < 16; ++ii) {
        int i2 = b2 * 16 + ii;
        if (i2 >= 50) break;
        int j = r + 4 * i2;
        float pj = __shfl(ev[b2], j & 63);
        acc += pj * Vs[j * 17 + dd];
      }
    }
    acc += __shfl_xor(acc, 1);
    acc += __shfl_xor(acc, 2);
    if (r == 0) ctx[base + p * 16 + dd] = acc * inv;
  }
}

// ---------------- pool + MLP head ----------------
__global__ __launch_bounds__(64) void k_head(const float* __restrict__ ctx,
    const float* __restrict__ ow, const float* __restrict__ ob,
    const float* __restrict__ w1, const float* __restrict__ b1,
    const float* __restrict__ w2, const float* __restrict__ b2,
    float* __restrict__ out) {
  __shared__ float ms[64], es[64];
  int g = blockIdx.x, t = threadIdx.x;
  int hh = t >> 4, dd = t & 15;
  const float* cb = ctx + (((size_t)g * 4 + hh) * 200) * 16 + dd;
  float s = 0.f;
  for (int p = 0; p < 200; ++p) s += cb[p * 16];
  ms[t] = s * (1.f / 200.f);
  __syncthreads();
  float e = ob[t];
  for (int j = 0; j < 64; ++j) e += ow[t * 64 + j] * ms[j];
  es[t] = e;
  __syncthreads();
  float h1 = b1[t];
  for (int j = 0; j < 64; ++j) h1 += w1[t * 64 + j] * es[j];
  h1 = fmaxf(h1, 0.f);
  float pr = h1 * w2[t];
  for (int off = 32; off >= 1; off >>= 1) pr += __shfl_xor(pr, off);
  if (t == 0) out[g] = pr + b2[0];
}

extern "C" void kernel_launch(void* const* d_in, const int* in_sizes, int n_in,
                              void* d_out, int out_size, void* d_ws, size_t ws_size,
                              hipStream_t stream) {
  (void)in_sizes; (void)n_in;
  const float* x      = (const float*)d_in[0];
  const int*   eidx   = (const int*)d_in[1];
  const float* ea     = (const float*)d_in[2];
  const float* en_w1  = (const float*)d_in[4];
  const float* en_b1  = (const float*)d_in[5];
  const float* en_w2  = (const float*)d_in[6];
  const float* en_b2  = (const float*)d_in[7];
  const float* root_w = (const float*)d_in[8];
  const float* conv_b = (const float*)d_in[9];
  const float* in_w   = (const float*)d_in[10];
  const float* in_b   = (const float*)d_in[11];
  const float* out_w  = (const float*)d_in[12];
  const float* out_b  = (const float*)d_in[13];
  const float* l1w    = (const float*)d_in[14];
  const float* l1b    = (const float*)d_in[15];
  const float* l2w    = (const float*)d_in[16];
  const float* l2b    = (const float*)d_in[17];
  float* out = (float*)d_out;

  // ---- workspace layout (bytes) ----
  char* w = (char*)d_ws;
  const size_t szA  = (size_t)1250 * NKB * 64 * 8 * 2;   // 84,480,000  bf16 A fragments
  unsigned short* Ap = (unsigned short*)w;
  char* r2 = w + szA;                                    // he (fp32, 40.96 MB) then reused
  float* he = (float*)r2;
  unsigned short* A2 = (unsigned short*)r2;              // 2,560,000 B (after he dead)
  float* Qb  = (float*)(r2 + 2560000);
  float* Kb  = (float*)(r2 + 7680000);
  float* Vb  = (float*)(r2 + 12800000);
  float* ctx = (float*)(r2 + 17920000);
  char* r3 = r2 + (size_t)N_E * 64 * 4;                  // after he region (40.96 MB)
  unsigned short* Bp  = (unsigned short*)r3;             // 270,336 B
  unsigned short* B2p = (unsigned short*)(r3 + 270336);  // 24,576 B
  int* starts = (int*)(r3 + 270336 + 24576);
  int* elist  = starts + (N_N + 4);
  int* cursor = elist + N_E;
  size_t need = szA + (size_t)N_E * 64 * 4 + 270336 + 24576
              + (size_t)(N_N + 4) * 4 + (size_t)N_E * 4 + (size_t)N_N * 4;
  if (ws_size < need || out_size < 100) return;

  hipMemsetAsync(cursor, 0, N_N * 4, stream);
  k_mlp1<<<N_E / 4, 256, 0, stream>>>(ea, en_w1, en_b1, he);
  k_hist<<<N_E / 256, 256, 0, stream>>>(eidx, cursor);
  k_scan<<<1, 1024, 0, stream>>>(cursor, starts);
  hipMemsetAsync(cursor, 0, N_N * 4, stream);
  k_scatter<<<N_E / 256, 256, 0, stream>>>(eidx, starts, cursor, elist);
  k_bt<<<528, 256, 0, stream>>>(en_w2, en_b2, root_w, Bp);
  k_bt2<<<48, 256, 0, stream>>>(in_w, B2p);
  k_pbuild<<<N_N, 256, 0, stream>>>(x, eidx, he, starts, elist, Ap);
  k_gemm_mfma<<<1250, 64, 0, stream>>>(Ap, Bp, starts, conv_b, A2);
  k_qkv_mfma<<<1250, 64, 0, stream>>>(A2, B2p, in_b, Qb, Kb, Vb);
  k_attn<<<400, 256, 0, stream>>>(Qb, Kb, Vb, ctx);
  k_head<<<100, 64, 0, stream>>>(ctx, out_w, out_b, l1w, l1b, l2w, l2b, out);
}

// Round 3
// 251.549 us; speedup vs baseline: 2.3256x; 1.3305x over previous
//
#include <hip/hip_runtime.h>
#include <math.h>

#define N_N 20000
#define N_E 160000
#define KA 2112   // A cols: 2048 (P) + 32 (xsum for b2) + 32 (x*cnt for root_w)
#define NKB 66

typedef __attribute__((ext_vector_type(8))) short bfrag;
typedef __attribute__((ext_vector_type(4))) float facc;

__device__ __forceinline__ unsigned short f2bf(float f) {
  union { float f; unsigned u; } v; v.f = f;
  unsigned u = v.u;
  return (unsigned short)((u + 0x7FFF + ((u >> 16) & 1)) >> 16);
}
__device__ __forceinline__ float bflo(unsigned u) {
  union { unsigned u; float f; } v; v.u = u << 16; return v.f;
}
__device__ __forceinline__ float bfhi(unsigned u) {
  union { unsigned u; float f; } v; v.u = u & 0xffff0000u; return v.f;
}

// ---------------- edge MLP layer 1 -> bf16 he ----------------
__global__ __launch_bounds__(256) void k_mlp1(const float* __restrict__ ea,
    const float* __restrict__ w1, const float* __restrict__ b1,
    unsigned short* __restrict__ he) {
  int t = threadIdx.x;
  int e = blockIdx.x * 4 + (t >> 6);
  int j = t & 63;
  const float* a = ea + (size_t)e * 16;
  const float* wr = w1 + j * 16;
  float s = b1[j];
#pragma unroll
  for (int i = 0; i < 16; ++i) s += a[i] * wr[i];
  he[(size_t)e * 64 + j] = f2bf(fmaxf(s, 0.f));
}

// ---------------- CSR build by dst ----------------
__global__ __launch_bounds__(256) void k_hist(const int* __restrict__ eidx,
    int* __restrict__ cnt) {
  int e = blockIdx.x * 256 + threadIdx.x;
  atomicAdd(&cnt[eidx[N_E + e]], 1);
}

__global__ __launch_bounds__(1024) void k_scan(const int* __restrict__ hist,
    int* __restrict__ starts) {
  __shared__ int part[1024];
  int t = threadIdx.x;
  const int CH = 20;
  int lo = t * CH;
  int hi = lo + CH; if (hi > N_N) hi = N_N;
  int s = 0;
  for (int i = lo; i < hi; ++i) s += hist[i];
  part[t] = s;
  __syncthreads();
  for (int off = 1; off < 1024; off <<= 1) {
    int v = (t >= off) ? part[t - off] : 0;
    __syncthreads();
    part[t] += v;
    __syncthreads();
  }
  int run = (t == 0) ? 0 : part[t - 1];
  for (int i = lo; i < hi; ++i) { starts[i] = run; run += hist[i]; }
  if (t == 1023) starts[N_N] = part[1023];
}

__global__ __launch_bounds__(256) void k_scatter(const int* __restrict__ eidx,
    const int* __restrict__ starts, int* __restrict__ cur,
    int* __restrict__ elist) {
  int e = blockIdx.x * 256 + threadIdx.x;
  int dn = eidx[N_E + e];
  int pos = atomicAdd(&cur[dn], 1);
  elist[starts[dn] + pos] = e;
}

// ---------------- B matrix [2112][64] packed into MFMA B-fragment layout (bf16) ----------
__global__ __launch_bounds__(256) void k_bt(const float* __restrict__ w2,
    const float* __restrict__ b2f, const float* __restrict__ rootw,
    unsigned short* __restrict__ Bp) {
  int idx = blockIdx.x * 256 + threadIdx.x;     // < 135168
  int i = idx & 7, l = (idx >> 3) & 63, cbkb = idx >> 9;
  int cb = cbkb & 3, kb = cbkb >> 2;
  int r = kb * 32 + ((l >> 4) << 3) + i;
  int c = (cb << 4) + (l & 15);
  float v;
  if (r < 2048) { int d = r >> 6, k = r & 63; v = w2[((d << 6) + c) * 64 + k]; }
  else if (r < 2080) v = b2f[((r - 2048) << 6) + c];
  else v = rootw[((r - 2080) << 6) + c];
  Bp[idx] = f2bf(v);
}

// ---------------- in_proj W packed for QKV MFMA ----------------
__global__ __launch_bounds__(256) void k_bt2(const float* __restrict__ inw,
    unsigned short* __restrict__ B2p) {
  int idx = blockIdx.x * 256 + threadIdx.x;     // < 12288
  int i = idx & 7, l = (idx >> 3) & 63, cbkb = idx >> 9;   // 0..23
  int cb = cbkb % 12, kb = cbkb / 12;
  int r = kb * 32 + ((l >> 4) << 3) + i;
  int c = (cb << 4) + (l & 15);
  B2p[idx] = f2bf(inw[c * 64 + r]);
}

// ---------------- per-node P accumulation -> row-major bf16 A ----------------
__global__ __launch_bounds__(256) void k_pbuild(const float* __restrict__ x,
    const int* __restrict__ eidx, const unsigned short* __restrict__ he,
    const int* __restrict__ starts, const int* __restrict__ elist,
    unsigned short* __restrict__ Ab) {
  int n = blockIdx.x;
  int tid = threadIdx.x;
  int d = tid >> 3;                 // 0..31
  int j8 = tid & 7;                 // he k-range j8*8..+7
  int s0 = starts[n], s1 = starts[n + 1];
  float a0 = 0.f, a1 = 0.f, a2 = 0.f, a3 = 0.f, a4 = 0.f, a5 = 0.f, a6 = 0.f, a7 = 0.f;
  float xs = 0.f;
  for (int i = s0; i < s1; ++i) {
    int e = elist[i];
    int src = eidx[e];
    float xv = x[src * 32 + d];
    uint4 hv = *(const uint4*)(he + (size_t)e * 64 + j8 * 8);
    a0 += xv * bflo(hv.x); a1 += xv * bfhi(hv.x);
    a2 += xv * bflo(hv.y); a3 += xv * bfhi(hv.y);
    a4 += xv * bflo(hv.z); a5 += xv * bfhi(hv.z);
    a6 += xv * bflo(hv.w); a7 += xv * bfhi(hv.w);
    if (tid < 32) xs += x[src * 32 + tid];
  }
  uint4 pk;
  pk.x = (unsigned)f2bf(a0) | ((unsigned)f2bf(a1) << 16);
  pk.y = (unsigned)f2bf(a2) | ((unsigned)f2bf(a3) << 16);
  pk.z = (unsigned)f2bf(a4) | ((unsigned)f2bf(a5) << 16);
  pk.w = (unsigned)f2bf(a6) | ((unsigned)f2bf(a7) << 16);
  *(uint4*)(Ab + (size_t)n * KA + tid * 8) = pk;   // col = d*64 + j8*8 == tid*8
  if (tid < 32) {
    int cnt = s1 - s0; if (cnt < 1) cnt = 1;
    Ab[(size_t)n * KA + 2048 + tid] = f2bf(xs);
    Ab[(size_t)n * KA + 2080 + tid] = f2bf(x[n * 32 + tid] * (float)cnt);
  }
}

// ---------------- MFMA GEMM [N,2112]x[2112,64], A row-major, N-split x2 ----------------
__global__ __launch_bounds__(256) void k_gemm_mfma(const unsigned short* __restrict__ Ab,
    const unsigned short* __restrict__ Bp, const int* __restrict__ starts,
    const float* __restrict__ convb, unsigned short* __restrict__ A2) {
  int t = threadIdx.x, l = t & 63;
  int W = blockIdx.x * 4 + (t >> 6);     // 0..2499
  int r0 = W >> 1, nh = W & 1;
  int col = l & 15, sub = l >> 4;
  const unsigned short* Arow = Ab + (size_t)(r0 * 16 + col) * KA + sub * 8;
  const bfrag* Bb = (const bfrag*)Bp + l + nh * 128;
  facc acc0 = {0.f, 0.f, 0.f, 0.f};
  facc acc1 = {0.f, 0.f, 0.f, 0.f};
#pragma unroll 3
  for (int kb = 0; kb < NKB; ++kb) {
    bfrag af = *(const bfrag*)(Arow + kb * 32);
    acc0 = __builtin_amdgcn_mfma_f32_16x16x32_bf16(af, Bb[kb * 256], acc0, 0, 0, 0);
    acc1 = __builtin_amdgcn_mfma_f32_16x16x32_bf16(af, Bb[kb * 256 + 64], acc1, 0, 0, 0);
  }
  float cv0 = convb[nh * 32 + col], cv1 = convb[nh * 32 + 16 + col];
#pragma unroll
  for (int j = 0; j < 4; ++j) {
    int m = (sub << 2) + j;
    int n = r0 * 16 + m;
    int cnt = starts[n + 1] - starts[n]; if (cnt < 1) cnt = 1;
    float inv = 1.f / (float)cnt;
    float v0 = fmaxf(acc0[j] * inv + cv0, 0.f);
    float v1 = fmaxf(acc1[j] * inv + cv1, 0.f);
    int c0 = nh * 32 + col, c1 = c0 + 16;
    A2[((size_t)(r0 * 2 + nh) * 64 + m + 16 * ((c0 >> 3) & 3)) * 8 + (c0 & 7)] = f2bf(v0);
    A2[((size_t)(r0 * 2 + nh) * 64 + m + 16 * ((c1 >> 3) & 3)) * 8 + (c1 & 7)] = f2bf(v1);
  }
}

// ---------------- QKV MFMA GEMM [N,64]x[64,192], scatter to [G][NH][200][16] --------------
__global__ __launch_bounds__(64) void k_qkv_mfma(const unsigned short* __restrict__ A2,
    const unsigned short* __restrict__ B2p, const float* __restrict__ inb,
    float* __restrict__ Qb, float* __restrict__ Kb, float* __restrict__ Vb) {
  int l = threadIdx.x;
  int r0 = blockIdx.x;
  const bfrag* A2r = (const bfrag*)A2 + (size_t)r0 * 128 + l;
  const bfrag* B2b = (const bfrag*)B2p + l;
  facc acc[12];
#pragma unroll
  for (int cb = 0; cb < 12; ++cb) { facc z = {0.f, 0.f, 0.f, 0.f}; acc[cb] = z; }
#pragma unroll
  for (int kb = 0; kb < 2; ++kb) {
    bfrag af = A2r[kb * 64];
#pragma unroll
    for (int cb = 0; cb < 12; ++cb)
      acc[cb] = __builtin_amdgcn_mfma_f32_16x16x32_bf16(af, B2b[(kb * 12 + cb) * 64], acc[cb], 0, 0, 0);
  }
  int col = l & 15;
#pragma unroll
  for (int j = 0; j < 4; ++j) {
    int n = r0 * 16 + ((l >> 4) << 2) + j;
    int g = n / 200, p = n - g * 200;
#pragma unroll
    for (int cb = 0; cb < 12; ++cb) {
      int c = cb * 16 + col;
      float v = acc[cb][j] + inb[c];
      int part = c >> 6, rem = c & 63, hh = rem >> 4, dd = rem & 15;
      float* dst = (part == 0) ? Qb : (part == 1 ? Kb : Vb);
      dst[(((size_t)g * 4 + hh) * 200 + p) * 16 + dd] = v;
    }
  }
}

// ---------------- MFMA flash attention: one block per (graph, head) ----------------
__global__ __launch_bounds__(256) void k_attn(const float* __restrict__ Qb,
    const float* __restrict__ Kb, const float* __restrict__ Vb,
    float* __restrict__ ctx) {
  __shared__ unsigned short Ks[224 * 24];   // row=key (padded 24/row for 16B-aligned b128)
  __shared__ unsigned short Vt[16 * 232];   // row=d, col=key (transposed), pad 232
  __shared__ unsigned short Pl[4][16 * 40]; // per-wave P tile, 80B rows
  int t = threadIdx.x;
  size_t base = (size_t)blockIdx.x * 3200;
  for (int idx = t; idx < 224 * 16; idx += 256) {
    int row = idx >> 4, d = idx & 15;
    float kv = (row < 200) ? Kb[base + idx] : 0.f;
    float vv = (row < 200) ? Vb[base + idx] : 0.f;
    Ks[row * 24 + d] = f2bf(kv);
    Vt[d * 232 + row] = f2bf(vv);
  }
  __syncthreads();
  int w = t >> 6, l = t & 63;
  int sub = l >> 4, col = l & 15;
  for (int qt = w; qt < 13; qt += 4) {
    bfrag qf = {0, 0, 0, 0, 0, 0, 0, 0};
    int q = qt * 16 + col;
    if (sub < 2 && q < 200) {
      const float* qp = Qb + base + q * 16 + sub * 8;
      float4 qa = *(const float4*)qp;
      float4 qb = *(const float4*)(qp + 4);
      qf[0] = (short)f2bf(qa.x); qf[1] = (short)f2bf(qa.y);
      qf[2] = (short)f2bf(qa.z); qf[3] = (short)f2bf(qa.w);
      qf[4] = (short)f2bf(qb.x); qf[5] = (short)f2bf(qb.y);
      qf[6] = (short)f2bf(qb.z); qf[7] = (short)f2bf(qb.w);
    }
    facc o = {0.f, 0.f, 0.f, 0.f};
    float srow0 = 0.f, srow1 = 0.f, srow2 = 0.f, srow3 = 0.f;
    for (int kt2 = 0; kt2 < 7; ++kt2) {
      int kt0 = kt2 * 2, kt1 = kt0 + 1;
      bfrag kf0 = {0, 0, 0, 0, 0, 0, 0, 0};
      bfrag kf1 = {0, 0, 0, 0, 0, 0, 0, 0};
      if (sub < 2) {
        kf0 = *(const bfrag*)&Ks[(kt0 * 16 + col) * 24 + sub * 8];
        kf1 = *(const bfrag*)&Ks[(kt1 * 16 + col) * 24 + sub * 8];
      }
      facc z = {0.f, 0.f, 0.f, 0.f};
      facc s0 = __builtin_amdgcn_mfma_f32_16x16x32_bf16(qf, kf0, z, 0, 0, 0);
      facc s1 = __builtin_amdgcn_mfma_f32_16x16x32_bf16(qf, kf1, z, 0, 0, 0);
      bool ok0 = (kt0 * 16 + col) < 200;
      bool ok1 = (kt1 * 16 + col) < 200;
#pragma unroll
      for (int j = 0; j < 4; ++j) {
        float e0 = ok0 ? __expf(s0[j] * 0.25f) : 0.f;
        float e1 = ok1 ? __expf(s1[j] * 0.25f) : 0.f;
        if (j == 0) { srow0 += e0 + e1; } else if (j == 1) { srow1 += e0 + e1; }
        else if (j == 2) { srow2 += e0 + e1; } else { srow3 += e0 + e1; }
        int qr = (sub << 2) + j;
        Pl[w][qr * 40 + col] = f2bf(e0);
        Pl[w][qr * 40 + 16 + col] = f2bf(e1);
      }
      bfrag pf = *(const bfrag*)&Pl[w][col * 40 + sub * 8];
      bfrag vf = *(const bfrag*)&Vt[col * 232 + kt2 * 32 + sub * 8];
      o = __builtin_amdgcn_mfma_f32_16x16x32_bf16(pf, vf, o, 0, 0, 0);
    }
#pragma unroll
    for (int off = 1; off < 16; off <<= 1) {
      srow0 += __shfl_xor(srow0, off);
      srow1 += __shfl_xor(srow1, off);
      srow2 += __shfl_xor(srow2, off);
      srow3 += __shfl_xor(srow3, off);
    }
#pragma unroll
    for (int j = 0; j < 4; ++j) {
      int qq = qt * 16 + (sub << 2) + j;
      float sr = (j == 0) ? srow0 : (j == 1) ? srow1 : (j == 2) ? srow2 : srow3;
      if (qq < 200) ctx[base + qq * 16 + col] = o[j] / sr;
    }
  }
}

// ---------------- pool + MLP head ----------------
__global__ __launch_bounds__(64) void k_head(const float* __restrict__ ctx,
    const float* __restrict__ ow, const float* __restrict__ ob,
    const float* __restrict__ w1, const float* __restrict__ b1,
    const float* __restrict__ w2, const float* __restrict__ b2,
    float* __restrict__ out) {
  __shared__ float ms[64], es[64];
  int g = blockIdx.x, t = threadIdx.x;
  int hh = t >> 4, dd = t & 15;
  const float* cb = ctx + (((size_t)g * 4 + hh) * 200) * 16 + dd;
  float s = 0.f;
  for (int p = 0; p < 200; ++p) s += cb[p * 16];
  ms[t] = s * (1.f / 200.f);
  __syncthreads();
  float e = ob[t];
  for (int j = 0; j < 64; ++j) e += ow[t * 64 + j] * ms[j];
  es[t] = e;
  __syncthreads();
  float h1 = b1[t];
  for (int j = 0; j < 64; ++j) h1 += w1[t * 64 + j] * es[j];
  h1 = fmaxf(h1, 0.f);
  float pr = h1 * w2[t];
  for (int off = 32; off >= 1; off >>= 1) pr += __shfl_xor(pr, off);
  if (t == 0) out[g] = pr + b2[0];
}

extern "C" void kernel_launch(void* const* d_in, const int* in_sizes, int n_in,
                              void* d_out, int out_size, void* d_ws, size_t ws_size,
                              hipStream_t stream) {
  (void)in_sizes; (void)n_in;
  const float* x      = (const float*)d_in[0];
  const int*   eidx   = (const int*)d_in[1];
  const float* ea     = (const float*)d_in[2];
  const float* en_w1  = (const float*)d_in[4];
  const float* en_b1  = (const float*)d_in[5];
  const float* en_w2  = (const float*)d_in[6];
  const float* en_b2  = (const float*)d_in[7];
  const float* root_w = (const float*)d_in[8];
  const float* conv_b = (const float*)d_in[9];
  const float* in_w   = (const float*)d_in[10];
  const float* in_b   = (const float*)d_in[11];
  const float* out_w  = (const float*)d_in[12];
  const float* out_b  = (const float*)d_in[13];
  const float* l1w    = (const float*)d_in[14];
  const float* l1b    = (const float*)d_in[15];
  const float* l2w    = (const float*)d_in[16];
  const float* l2b    = (const float*)d_in[17];
  float* out = (float*)d_out;

  // ---- workspace layout (bytes) ----
  char* w = (char*)d_ws;
  const size_t szAb = (size_t)N_N * KA * 2;        // 84,480,000 bf16 row-major A
  unsigned short* Ab = (unsigned short*)w;
  char* r2 = w + szAb;
  unsigned short* he = (unsigned short*)r2;        // 20,480,000 (dead after pbuild)
  unsigned short* A2 = (unsigned short*)r2;        // 2,560,000 (after he dead)
  float* Qb  = (float*)(r2 + 2560000);
  float* Kb  = (float*)(r2 + 7680000);
  float* Vb  = (float*)(r2 + 12800000);
  float* ctx = (float*)(r2 + 17920000);            // ends at 23,040,000
  char* r3 = r2 + 23040000;
  unsigned short* Bp  = (unsigned short*)r3;             // 270,336
  unsigned short* B2p = (unsigned short*)(r3 + 270336);  // 24,576
  int* starts = (int*)(r3 + 270336 + 24576);
  int* elist  = starts + (N_N + 4);
  int* cursor = elist + N_E;
  size_t need = szAb + 23040000 + 270336 + 24576
              + (size_t)(N_N + 4) * 4 + (size_t)N_E * 4 + (size_t)N_N * 4;
  if (ws_size < need || out_size < 100) return;

  hipMemsetAsync(cursor, 0, N_N * 4, stream);
  k_mlp1<<<N_E / 4, 256, 0, stream>>>(ea, en_w1, en_b1, he);
  k_hist<<<N_E / 256, 256, 0, stream>>>(eidx, cursor);
  k_scan<<<1, 1024, 0, stream>>>(cursor, starts);
  hipMemsetAsync(cursor, 0, N_N * 4, stream);
  k_scatter<<<N_E / 256, 256, 0, stream>>>(eidx, starts, cursor, elist);
  k_bt<<<528, 256, 0, stream>>>(en_w2, en_b2, root_w, Bp);
  k_bt2<<<48, 256, 0, stream>>>(in_w, B2p);
  k_pbuild<<<N_N, 256, 0, stream>>>(x, eidx, he, starts, elist, Ab);
  k_gemm_mfma<<<625, 256, 0, stream>>>(Ab, Bp, starts, conv_b, A2);
  k_qkv_mfma<<<1250, 64, 0, stream>>>(A2, B2p, in_b, Qb, Kb, Vb);
  k_attn<<<400, 256, 0, stream>>>(Qb, Kb, Vb, ctx);
  k_head<<<100, 64, 0, stream>>>(ctx, out_w, out_b, l1w, l1b, l2w, l2b, out);
}

// Round 4
// 215.524 us; speedup vs baseline: 2.7143x; 1.1671x over previous
//
#include <hip/hip_runtime.h>
#include <math.h>

#define N_N 20000
#define N_E 160000
#define KA 2112   // A cols: 2048 (P) + 32 (xsum for b2) + 32 (x*cnt for root_w)
#define NKB 66

typedef __attribute__((ext_vector_type(8))) short bfrag;
typedef __attribute__((ext_vector_type(4))) float facc;

__device__ __forceinline__ unsigned short f2bf(float f) {
  union { float f; unsigned u; } v; v.f = f;
  unsigned u = v.u;
  return (unsigned short)((u + 0x7FFF + ((u >> 16) & 1)) >> 16);
}
__device__ __forceinline__ unsigned pk2(float a, float b) {
  return (unsigned)f2bf(a) | ((unsigned)f2bf(b) << 16);
}
__device__ __forceinline__ float bflo(unsigned u) {
  union { unsigned u; float f; } v; v.u = u << 16; return v.f;
}
__device__ __forceinline__ float bfhi(unsigned u) {
  union { unsigned u; float f; } v; v.u = u & 0xffff0000u; return v.f;
}

// ---------------- edge MLP layer 1 -> bf16 he (w1 in regs, 8 edges/wave) ----------------
__global__ __launch_bounds__(256) void k_mlp1(const float* __restrict__ ea,
    const float* __restrict__ w1, const float* __restrict__ b1,
    unsigned short* __restrict__ he) {
  int t = threadIdx.x, w = t >> 6, j = t & 63;
  int e0 = (blockIdx.x * 4 + w) * 8;
  float wr[16];
#pragma unroll
  for (int i = 0; i < 16; ++i) wr[i] = w1[j * 16 + i];
  float bj = b1[j];
#pragma unroll
  for (int q = 0; q < 8; ++q) {
    int e = e0 + q;
    const float* a = ea + (size_t)e * 16;
    float s = bj;
#pragma unroll
    for (int i = 0; i < 16; ++i) s += a[i] * wr[i];
    he[(size_t)e * 64 + j] = f2bf(fmaxf(s, 0.f));
  }
}

// ---------------- CSR build by dst ----------------
__global__ __launch_bounds__(256) void k_hist(const int* __restrict__ eidx,
    int* __restrict__ cnt) {
  int e = blockIdx.x * 256 + threadIdx.x;
  atomicAdd(&cnt[eidx[N_E + e]], 1);
}

// scan also seeds the scatter cursor (cur aliases hist -> careful ordering)
__global__ __launch_bounds__(1024) void k_scan(int* __restrict__ hist,
    int* __restrict__ starts) {
  __shared__ int part[1024];
  int t = threadIdx.x;
  const int CH = 20;
  int lo = t * CH;
  int hi = lo + CH; if (hi > N_N) hi = N_N;
  int s = 0;
  for (int i = lo; i < hi; ++i) s += hist[i];
  part[t] = s;
  __syncthreads();
  for (int off = 1; off < 1024; off <<= 1) {
    int v = (t >= off) ? part[t - off] : 0;
    __syncthreads();
    part[t] += v;
    __syncthreads();
  }
  int run = (t == 0) ? 0 : part[t - 1];
  for (int i = lo; i < hi; ++i) {
    int h = hist[i];
    starts[i] = run;
    hist[i] = run;          // becomes cursor seed
    run += h;
  }
  if (t == 1023) starts[N_N] = part[1023];
}

__global__ __launch_bounds__(256) void k_scatter(const int* __restrict__ eidx,
    int* __restrict__ cur, int* __restrict__ elist, int* __restrict__ srcl) {
  int e = blockIdx.x * 256 + threadIdx.x;
  int dn = eidx[N_E + e];
  int pos = atomicAdd(&cur[dn], 1);
  elist[pos] = e;
  srcl[pos] = eidx[e];
}

// ---------------- pack B (gemm), B2 (qkv) fragment layouts ----------------
__global__ __launch_bounds__(256) void k_pack(const float* __restrict__ w2,
    const float* __restrict__ b2f, const float* __restrict__ rootw,
    const float* __restrict__ inw,
    unsigned short* __restrict__ Bp, unsigned short* __restrict__ B2p) {
  int idx = blockIdx.x * 256 + threadIdx.x;
  if (idx < 135168) {
    int i = idx & 7, l = (idx >> 3) & 63, cbkb = idx >> 9;
    int cb = cbkb & 3, kb = cbkb >> 2;
    int r = kb * 32 + ((l >> 4) << 3) + i;
    int c = (cb << 4) + (l & 15);
    float v;
    if (r < 2048) { int d = r >> 6, k = r & 63; v = w2[((d << 6) + c) * 64 + k]; }
    else if (r < 2080) v = b2f[((r - 2048) << 6) + c];
    else v = rootw[((r - 2080) << 6) + c];
    Bp[idx] = f2bf(v);
  } else if (idx < 135168 + 12288) {
    int k2 = idx - 135168;
    int i = k2 & 7, l = (k2 >> 3) & 63, cbkb = k2 >> 9;   // 0..23
    int cb = cbkb % 12, kb = cbkb / 12;
    int r = kb * 32 + ((l >> 4) << 3) + i;
    int c = (cb << 4) + (l & 15);
    B2p[k2] = f2bf(inw[c * 64 + r]);
  }
}

// ---------------- per-node P accumulation: one WAVE per node, 32 acc/lane --------------
#define FMA8(hv, base, xv) \
  acc[base + 0] += xv * bflo(hv.x); acc[base + 1] += xv * bfhi(hv.x); \
  acc[base + 2] += xv * bflo(hv.y); acc[base + 3] += xv * bfhi(hv.y); \
  acc[base + 4] += xv * bflo(hv.z); acc[base + 5] += xv * bfhi(hv.z); \
  acc[base + 6] += xv * bflo(hv.w); acc[base + 7] += xv * bfhi(hv.w);

__global__ __launch_bounds__(256) void k_pbuild(const float* __restrict__ x,
    const unsigned short* __restrict__ he, const int* __restrict__ starts,
    const int* __restrict__ elist, const int* __restrict__ srcl,
    unsigned short* __restrict__ Ab) {
  int t = threadIdx.x, w = t >> 6, l = t & 63;
  int n = blockIdx.x * 4 + w;
  int d = l >> 1, half = l & 1;
  int s0 = starts[n], s1 = starts[n + 1];
  float acc[32];
#pragma unroll
  for (int i = 0; i < 32; ++i) acc[i] = 0.f;
  float xs = 0.f;
  int i = s0;
  for (; i + 1 < s1; i += 2) {
    int e0 = elist[i], e1 = elist[i + 1];
    int sr0 = srcl[i], sr1 = srcl[i + 1];
    float xv0 = x[sr0 * 32 + d];
    float xv1 = x[sr1 * 32 + d];
    const uint4* hp0 = (const uint4*)(he + (size_t)e0 * 64 + half * 32);
    const uint4* hp1 = (const uint4*)(he + (size_t)e1 * 64 + half * 32);
    uint4 a0 = hp0[0], a1 = hp0[1], a2 = hp0[2], a3 = hp0[3];
    uint4 b0 = hp1[0], b1 = hp1[1], b2 = hp1[2], b3 = hp1[3];
    FMA8(a0, 0, xv0) FMA8(a1, 8, xv0) FMA8(a2, 16, xv0) FMA8(a3, 24, xv0)
    FMA8(b0, 0, xv1) FMA8(b1, 8, xv1) FMA8(b2, 16, xv1) FMA8(b3, 24, xv1)
    xs += xv0 + xv1;
  }
  if (i < s1) {
    int e0 = elist[i];
    int sr0 = srcl[i];
    float xv0 = x[sr0 * 32 + d];
    const uint4* hp0 = (const uint4*)(he + (size_t)e0 * 64 + half * 32);
    uint4 a0 = hp0[0], a1 = hp0[1], a2 = hp0[2], a3 = hp0[3];
    FMA8(a0, 0, xv0) FMA8(a1, 8, xv0) FMA8(a2, 16, xv0) FMA8(a3, 24, xv0)
    xs += xv0;
  }
  uint4 o0, o1, o2, o3;
  o0.x = pk2(acc[0], acc[1]);   o0.y = pk2(acc[2], acc[3]);
  o0.z = pk2(acc[4], acc[5]);   o0.w = pk2(acc[6], acc[7]);
  o1.x = pk2(acc[8], acc[9]);   o1.y = pk2(acc[10], acc[11]);
  o1.z = pk2(acc[12], acc[13]); o1.w = pk2(acc[14], acc[15]);
  o2.x = pk2(acc[16], acc[17]); o2.y = pk2(acc[18], acc[19]);
  o2.z = pk2(acc[20], acc[21]); o2.w = pk2(acc[22], acc[23]);
  o3.x = pk2(acc[24], acc[25]); o3.y = pk2(acc[26], acc[27]);
  o3.z = pk2(acc[28], acc[29]); o3.w = pk2(acc[30], acc[31]);
  uint4* row = (uint4*)(Ab + (size_t)n * KA + l * 32);
  row[0] = o0; row[1] = o1; row[2] = o2; row[3] = o3;
  if (half == 0) {
    int cnt = s1 - s0; if (cnt < 1) cnt = 1;
    Ab[(size_t)n * KA + 2048 + d] = f2bf(xs);
    Ab[(size_t)n * KA + 2080 + d] = f2bf(x[n * 32 + d] * (float)cnt);
  }
}

// ---------------- MFMA GEMM [N,2112]x[2112,64] + mean/bias/relu + fused QKV ------------
__global__ __launch_bounds__(256) void k_gemm_mfma(const unsigned short* __restrict__ Ab,
    const unsigned short* __restrict__ Bp, const unsigned short* __restrict__ B2p,
    const int* __restrict__ starts, const float* __restrict__ convb,
    const float* __restrict__ inb,
    float* __restrict__ Qb, float* __restrict__ Kb, float* __restrict__ Vb) {
  __shared__ unsigned short xhT[2][16 * 64];
  int t = threadIdx.x, w = t >> 6, l = t & 63;
  int W = blockIdx.x * 4 + w;
  int r0 = W >> 1, nh = W & 1, rg = w >> 1;
  int col = l & 15, sub = l >> 4;
  const unsigned short* Arow = Ab + (size_t)(r0 * 16 + col) * KA + sub * 8;
  const bfrag* Bb = (const bfrag*)Bp + l + nh * 128;
  facc acc0 = {0.f, 0.f, 0.f, 0.f};
  facc acc1 = {0.f, 0.f, 0.f, 0.f};
#pragma unroll 3
  for (int kb = 0; kb < NKB; ++kb) {
    bfrag af = *(const bfrag*)(Arow + kb * 32);
    acc0 = __builtin_amdgcn_mfma_f32_16x16x32_bf16(af, Bb[kb * 256], acc0, 0, 0, 0);
    acc1 = __builtin_amdgcn_mfma_f32_16x16x32_bf16(af, Bb[kb * 256 + 64], acc1, 0, 0, 0);
  }
  float cv0 = convb[nh * 32 + col], cv1 = convb[nh * 32 + 16 + col];
#pragma unroll
  for (int j = 0; j < 4; ++j) {
    int m = (sub << 2) + j;
    int n = r0 * 16 + m;
    int cnt = starts[n + 1] - starts[n]; if (cnt < 1) cnt = 1;
    float inv = 1.f / (float)cnt;
    xhT[rg][m * 64 + nh * 32 + col]      = f2bf(fmaxf(acc0[j] * inv + cv0, 0.f));
    xhT[rg][m * 64 + nh * 32 + 16 + col] = f2bf(fmaxf(acc1[j] * inv + cv1, 0.f));
  }
  __syncthreads();
  // ---- fused QKV: wave handles its rg tile, col-block range (w&1)*6..+6 ----
  bfrag af0 = *(const bfrag*)&xhT[rg][col * 64 + sub * 8];
  bfrag af1 = *(const bfrag*)&xhT[rg][col * 64 + 32 + sub * 8];
  const bfrag* B2b = (const bfrag*)B2p + l;
  int cb0 = (w & 1) * 6;
  facc qacc[6];
#pragma unroll
  for (int cb = 0; cb < 6; ++cb) { facc z = {0.f, 0.f, 0.f, 0.f}; qacc[cb] = z; }
#pragma unroll
  for (int cb = 0; cb < 6; ++cb) {
    qacc[cb] = __builtin_amdgcn_mfma_f32_16x16x32_bf16(af0, B2b[(cb0 + cb) * 64], qacc[cb], 0, 0, 0);
    qacc[cb] = __builtin_amdgcn_mfma_f32_16x16x32_bf16(af1, B2b[(12 + cb0 + cb) * 64], qacc[cb], 0, 0, 0);
  }
  int r0q = blockIdx.x * 2 + rg;
#pragma unroll
  for (int j = 0; j < 4; ++j) {
    int n = r0q * 16 + (sub << 2) + j;
    int g = n / 200, p = n - g * 200;
#pragma unroll
    for (int cb = 0; cb < 6; ++cb) {
      int c = (cb0 + cb) * 16 + col;
      float v = qacc[cb][j] + inb[c];
      int part = c >> 6, rem = c & 63, hh = rem >> 4, dd = rem & 15;
      float* dst = (part == 0) ? Qb : (part == 1 ? Kb : Vb);
      dst[(((size_t)g * 4 + hh) * 200 + p) * 16 + dd] = v;
    }
  }
}

// ---------------- MFMA flash attention: one block per (graph, head) ----------------
__global__ __launch_bounds__(256) void k_attn(const float* __restrict__ Qb,
    const float* __restrict__ Kb, const float* __restrict__ Vb,
    float* __restrict__ ctx) {
  __shared__ unsigned short Ks[224 * 24];
  __shared__ unsigned short Vt[16 * 232];
  __shared__ unsigned short Pl[4][16 * 40];
  int t = threadIdx.x;
  size_t base = (size_t)blockIdx.x * 3200;
  for (int idx = t; idx < 224 * 16; idx += 256) {
    int row = idx >> 4, d = idx & 15;
    float kv = (row < 200) ? Kb[base + idx] : 0.f;
    float vv = (row < 200) ? Vb[base + idx] : 0.f;
    Ks[row * 24 + d] = f2bf(kv);
    Vt[d * 232 + row] = f2bf(vv);
  }
  __syncthreads();
  int w = t >> 6, l = t & 63;
  int sub = l >> 4, col = l & 15;
  for (int qt = w; qt < 13; qt += 4) {
    bfrag qf = {0, 0, 0, 0, 0, 0, 0, 0};
    int q = qt * 16 + col;
    if (sub < 2 && q < 200) {
      const float* qp = Qb + base + q * 16 + sub * 8;
      float4 qa = *(const float4*)qp;
      float4 qb = *(const float4*)(qp + 4);
      qf[0] = (short)f2bf(qa.x); qf[1] = (short)f2bf(qa.y);
      qf[2] = (short)f2bf(qa.z); qf[3] = (short)f2bf(qa.w);
      qf[4] = (short)f2bf(qb.x); qf[5] = (short)f2bf(qb.y);
      qf[6] = (short)f2bf(qb.z); qf[7] = (short)f2bf(qb.w);
    }
    facc o = {0.f, 0.f, 0.f, 0.f};
    float srow0 = 0.f, srow1 = 0.f, srow2 = 0.f, srow3 = 0.f;
    for (int kt2 = 0; kt2 < 7; ++kt2) {
      int kt0 = kt2 * 2, kt1 = kt0 + 1;
      bfrag kf0 = {0, 0, 0, 0, 0, 0, 0, 0};
      bfrag kf1 = {0, 0, 0, 0, 0, 0, 0, 0};
      if (sub < 2) {
        kf0 = *(const bfrag*)&Ks[(kt0 * 16 + col) * 24 + sub * 8];
        kf1 = *(const bfrag*)&Ks[(kt1 * 16 + col) * 24 + sub * 8];
      }
      facc z = {0.f, 0.f, 0.f, 0.f};
      facc s0 = __builtin_amdgcn_mfma_f32_16x16x32_bf16(qf, kf0, z, 0, 0, 0);
      facc s1 = __builtin_amdgcn_mfma_f32_16x16x32_bf16(qf, kf1, z, 0, 0, 0);
      bool ok0 = (kt0 * 16 + col) < 200;
      bool ok1 = (kt1 * 16 + col) < 200;
#pragma unroll
      for (int j = 0; j < 4; ++j) {
        float e0 = ok0 ? __expf(s0[j] * 0.25f) : 0.f;
        float e1 = ok1 ? __expf(s1[j] * 0.25f) : 0.f;
        if (j == 0) { srow0 += e0 + e1; } else if (j == 1) { srow1 += e0 + e1; }
        else if (j == 2) { srow2 += e0 + e1; } else { srow3 += e0 + e1; }
        int qr = (sub << 2) + j;
        Pl[w][qr * 40 + col] = f2bf(e0);
        Pl[w][qr * 40 + 16 + col] = f2bf(e1);
      }
      bfrag pf = *(const bfrag*)&Pl[w][col * 40 + sub * 8];
      bfrag vf = *(const bfrag*)&Vt[col * 232 + kt2 * 32 + sub * 8];
      o = __builtin_amdgcn_mfma_f32_16x16x32_bf16(pf, vf, o, 0, 0, 0);
    }
#pragma unroll
    for (int off = 1; off < 16; off <<= 1) {
      srow0 += __shfl_xor(srow0, off);
      srow1 += __shfl_xor(srow1, off);
      srow2 += __shfl_xor(srow2, off);
      srow3 += __shfl_xor(srow3, off);
    }
#pragma unroll
    for (int j = 0; j < 4; ++j) {
      int qq = qt * 16 + (sub << 2) + j;
      float sr = (j == 0) ? srow0 : (j == 1) ? srow1 : (j == 2) ? srow2 : srow3;
      if (qq < 200) ctx[base + qq * 16 + col] = o[j] / sr;
    }
  }
}

// ---------------- pool + MLP head ----------------
__global__ __launch_bounds__(64) void k_head(const float* __restrict__ ctx,
    const float* __restrict__ ow, const float* __restrict__ ob,
    const float* __restrict__ w1, const float* __restrict__ b1,
    const float* __restrict__ w2, const float* __restrict__ b2,
    float* __restrict__ out) {
  __shared__ float ms[64], es[64];
  int g = blockIdx.x, t = threadIdx.x;
  int hh = t >> 4, dd = t & 15;
  const float* cb = ctx + (((size_t)g * 4 + hh) * 200) * 16 + dd;
  float s = 0.f;
  for (int p = 0; p < 200; ++p) s += cb[p * 16];
  ms[t] = s * (1.f / 200.f);
  __syncthreads();
  float e = ob[t];
  for (int j = 0; j < 64; ++j) e += ow[t * 64 + j] * ms[j];
  es[t] = e;
  __syncthreads();
  float h1 = b1[t];
  for (int j = 0; j < 64; ++j) h1 += w1[t * 64 + j] * es[j];
  h1 = fmaxf(h1, 0.f);
  float pr = h1 * w2[t];
  for (int off = 32; off >= 1; off >>= 1) pr += __shfl_xor(pr, off);
  if (t == 0) out[g] = pr + b2[0];
}

extern "C" void kernel_launch(void* const* d_in, const int* in_sizes, int n_in,
                              void* d_out, int out_size, void* d_ws, size_t ws_size,
                              hipStream_t stream) {
  (void)in_sizes; (void)n_in;
  const float* x      = (const float*)d_in[0];
  const int*   eidx   = (const int*)d_in[1];
  const float* ea     = (const float*)d_in[2];
  const float* en_w1  = (const float*)d_in[4];
  const float* en_b1  = (const float*)d_in[5];
  const float* en_w2  = (const float*)d_in[6];
  const float* en_b2  = (const float*)d_in[7];
  const float* root_w = (const float*)d_in[8];
  const float* conv_b = (const float*)d_in[9];
  const float* in_w   = (const float*)d_in[10];
  const float* in_b   = (const float*)d_in[11];
  const float* out_w  = (const float*)d_in[12];
  const float* out_b  = (const float*)d_in[13];
  const float* l1w    = (const float*)d_in[14];
  const float* l1b    = (const float*)d_in[15];
  const float* l2w    = (const float*)d_in[16];
  const float* l2b    = (const float*)d_in[17];
  float* out = (float*)d_out;

  // ---- workspace layout (bytes) ----
  char* w = (char*)d_ws;
  const size_t szAb = (size_t)N_N * KA * 2;        // 84,480,000 bf16 row-major A
  unsigned short* Ab = (unsigned short*)w;
  char* r2 = w + szAb;
  unsigned short* he = (unsigned short*)r2;        // 20,480,000 (dead after pbuild)
  float* Qb  = (float*)r2;                         // reuses he region after pbuild
  float* Kb  = (float*)(r2 + 5120000);
  float* Vb  = (float*)(r2 + 10240000);
  float* ctx = (float*)(r2 + 15360000);            // ends at 20,480,000
  char* r3 = r2 + 20480000;
  unsigned short* Bp  = (unsigned short*)r3;             // 270,336
  unsigned short* B2p = (unsigned short*)(r3 + 270336);  // 24,576
  int* starts = (int*)(r3 + 270336 + 24576);
  int* elist  = starts + (N_N + 4);
  int* srcl   = elist + N_E;
  int* cursor = srcl + N_E;
  size_t need = szAb + 20480000 + 270336 + 24576
              + (size_t)(N_N + 4) * 4 + 2 * (size_t)N_E * 4 + (size_t)N_N * 4;
  if (ws_size < need || out_size < 100) return;

  hipMemsetAsync(cursor, 0, N_N * 4, stream);
  k_pack<<<580, 256, 0, stream>>>(en_w2, en_b2, root_w, in_w, Bp, B2p);
  k_hist<<<N_E / 256, 256, 0, stream>>>(eidx, cursor);
  k_scan<<<1, 1024, 0, stream>>>(cursor, starts);
  k_scatter<<<N_E / 256, 256, 0, stream>>>(eidx, cursor, elist, srcl);
  k_mlp1<<<5000, 256, 0, stream>>>(ea, en_w1, en_b1, he);
  k_pbuild<<<5000, 256, 0, stream>>>(x, he, starts, elist, srcl, Ab);
  k_gemm_mfma<<<625, 256, 0, stream>>>(Ab, Bp, B2p, starts, conv_b, in_b, Qb, Kb, Vb);
  k_attn<<<400, 256, 0, stream>>>(Qb, Kb, Vb, ctx);
  k_head<<<100, 64, 0, stream>>>(ctx, out_w, out_b, l1w, l1b, l2w, l2b, out);
}

// Round 5
// 186.924 us; speedup vs baseline: 3.1296x; 1.1530x over previous
//
#include <hip/hip_runtime.h>
#include <math.h>

#define N_N 20000
#define N_E 160000
#define KA 2112   // A cols: 2048 (P) + 32 (xsum for b2) + 32 (x*cnt for root_w)
#define NKB 66

typedef __attribute__((ext_vector_type(8))) short bfrag;
typedef __attribute__((ext_vector_type(4))) float facc;

__device__ __forceinline__ unsigned short f2bf(float f) {
  union { float f; unsigned u; } v; v.f = f;
  unsigned u = v.u;
  return (unsigned short)((u + 0x7FFF + ((u >> 16) & 1)) >> 16);
}
__device__ __forceinline__ unsigned pk2(float a, float b) {
  return (unsigned)f2bf(a) | ((unsigned)f2bf(b) << 16);
}
__device__ __forceinline__ float bflo(unsigned u) {
  union { unsigned u; float f; } v; v.u = u << 16; return v.f;
}
__device__ __forceinline__ float bfhi(unsigned u) {
  union { unsigned u; float f; } v; v.u = u & 0xffff0000u; return v.f;
}

// ---------------- edge MLP layer 1 -> bf16 he, written PERMUTED to dst-sorted order ------
__global__ __launch_bounds__(256) void k_mlp1(const float* __restrict__ ea,
    const float* __restrict__ w1, const float* __restrict__ b1,
    const int* __restrict__ perm, unsigned short* __restrict__ hes) {
  int t = threadIdx.x, w = t >> 6, j = t & 63;
  int e0 = (blockIdx.x * 4 + w) * 8;
  float wr[16];
#pragma unroll
  for (int i = 0; i < 16; ++i) wr[i] = w1[j * 16 + i];
  float bj = b1[j];
#pragma unroll
  for (int q = 0; q < 8; ++q) {
    int e = e0 + q;
    const float* a = ea + (size_t)e * 16;
    float s = bj;
#pragma unroll
    for (int i = 0; i < 16; ++i) s += a[i] * wr[i];
    hes[(size_t)perm[e] * 64 + j] = f2bf(fmaxf(s, 0.f));
  }
}

// ---------------- CSR build by dst ----------------
__global__ __launch_bounds__(256) void k_hist(const int* __restrict__ eidx,
    int* __restrict__ cnt) {
  int e = blockIdx.x * 256 + threadIdx.x;
  atomicAdd(&cnt[eidx[N_E + e]], 1);
}

// scan also seeds the scatter cursor (cur aliases hist)
__global__ __launch_bounds__(1024) void k_scan(int* __restrict__ hist,
    int* __restrict__ starts) {
  __shared__ int part[1024];
  int t = threadIdx.x;
  const int CH = 20;
  int lo = t * CH;
  int hi = lo + CH; if (hi > N_N) hi = N_N;
  int s = 0;
  for (int i = lo; i < hi; ++i) s += hist[i];
  part[t] = s;
  __syncthreads();
  for (int off = 1; off < 1024; off <<= 1) {
    int v = (t >= off) ? part[t - off] : 0;
    __syncthreads();
    part[t] += v;
    __syncthreads();
  }
  int run = (t == 0) ? 0 : part[t - 1];
  for (int i = lo; i < hi; ++i) {
    int h = hist[i];
    starts[i] = run;
    hist[i] = run;          // cursor seed
    run += h;
  }
  if (t == 1023) starts[N_N] = part[1023];
}

__global__ __launch_bounds__(256) void k_scatter(const int* __restrict__ eidx,
    int* __restrict__ cur, int* __restrict__ perm, int* __restrict__ srcl) {
  int e = blockIdx.x * 256 + threadIdx.x;
  int dn = eidx[N_E + e];
  int pos = atomicAdd(&cur[dn], 1);
  perm[e] = pos;
  srcl[pos] = eidx[e];
}

// ---------------- pack B (gemm), B2 (qkv) fragment layouts ----------------
__global__ __launch_bounds__(256) void k_pack(const float* __restrict__ w2,
    const float* __restrict__ b2f, const float* __restrict__ rootw,
    const float* __restrict__ inw,
    unsigned short* __restrict__ Bp, unsigned short* __restrict__ B2p) {
  int idx = blockIdx.x * 256 + threadIdx.x;
  if (idx < 135168) {
    int i = idx & 7, l = (idx >> 3) & 63, cbkb = idx >> 9;
    int cb = cbkb & 3, kb = cbkb >> 2;
    int r = kb * 32 + ((l >> 4) << 3) + i;
    int c = (cb << 4) + (l & 15);
    float v;
    if (r < 2048) { int d = r >> 6, k = r & 63; v = w2[((d << 6) + c) * 64 + k]; }
    else if (r < 2080) v = b2f[((r - 2048) << 6) + c];
    else v = rootw[((r - 2080) << 6) + c];
    Bp[idx] = f2bf(v);
  } else if (idx < 135168 + 12288) {
    int k2 = idx - 135168;
    int i = k2 & 7, l = (k2 >> 3) & 63, cbkb = k2 >> 9;
    int cb = cbkb % 12, kb = cbkb / 12;
    int r = kb * 32 + ((l >> 4) << 3) + i;
    int c = (cb << 4) + (l & 15);
    B2p[k2] = f2bf(inw[c * 64 + r]);
  }
}

// ---------------- FUSED: P-build (LDS) + MFMA GEMM + mean/bias/relu + QKV ----------------
// Block = 16 nodes (one MFMA row tile). P in LDS, chunk-swizzled: chunk c of row m
// stored at chunk (c ^ (m&7)). Lane l owns chunks {l, l+64, l+128, l+192} (k = 8*chunk..+8).
#define FMA8(hv, base, xv) \
  acc[base + 0] += xv * bflo(hv.x); acc[base + 1] += xv * bfhi(hv.x); \
  acc[base + 2] += xv * bflo(hv.y); acc[base + 3] += xv * bfhi(hv.y); \
  acc[base + 4] += xv * bflo(hv.z); acc[base + 5] += xv * bfhi(hv.z); \
  acc[base + 6] += xv * bflo(hv.w); acc[base + 7] += xv * bfhi(hv.w);

__global__ __launch_bounds__(256) void k_fused(const float* __restrict__ x,
    const unsigned short* __restrict__ hes, const int* __restrict__ starts,
    const int* __restrict__ srcl,
    const unsigned short* __restrict__ Bp, const unsigned short* __restrict__ B2p,
    const float* __restrict__ convb, const float* __restrict__ inb,
    float* __restrict__ Qb, float* __restrict__ Kb, float* __restrict__ Vb) {
  __shared__ unsigned short Ps[16 * KA];     // 67,584 B
  __shared__ unsigned short xhT[16 * 68];    //  2,176 B
  int t = threadIdx.x, w = t >> 6, l = t & 63;
  int n0 = blockIdx.x * 16;
  int d0 = l >> 3, hc = (l & 7) * 8;
  // ---- phase 1: each wave builds 4 node rows of P ----
#pragma unroll 1
  for (int i4 = 0; i4 < 4; ++i4) {
    int m = w * 4 + i4;
    int n = n0 + m;
    int s0 = starts[n], s1 = starts[n + 1];
    float acc[32];
#pragma unroll
    for (int z = 0; z < 32; ++z) acc[z] = 0.f;
    float xs = 0.f;
    int i = s0;
    for (; i + 1 < s1; i += 2) {
      int sr0 = srcl[i], sr1 = srcl[i + 1];
      uint4 h0 = *(const uint4*)(hes + (size_t)i * 64 + hc);
      uint4 h1 = *(const uint4*)(hes + (size_t)(i + 1) * 64 + hc);
      const float* xr0 = x + sr0 * 32;
      const float* xr1 = x + sr1 * 32;
      float a0 = xr0[d0], a1 = xr0[d0 + 8], a2 = xr0[d0 + 16], a3 = xr0[d0 + 24];
      float b0 = xr1[d0], b1 = xr1[d0 + 8], b2 = xr1[d0 + 16], b3 = xr1[d0 + 24];
      FMA8(h0, 0, a0) FMA8(h0, 8, a1) FMA8(h0, 16, a2) FMA8(h0, 24, a3)
      FMA8(h1, 0, b0) FMA8(h1, 8, b1) FMA8(h1, 16, b2) FMA8(h1, 24, b3)
      if (l < 32) xs += xr0[l] + xr1[l];
    }
    if (i < s1) {
      int sr0 = srcl[i];
      uint4 h0 = *(const uint4*)(hes + (size_t)i * 64 + hc);
      const float* xr0 = x + sr0 * 32;
      float a0 = xr0[d0], a1 = xr0[d0 + 8], a2 = xr0[d0 + 16], a3 = xr0[d0 + 24];
      FMA8(h0, 0, a0) FMA8(h0, 8, a1) FMA8(h0, 16, a2) FMA8(h0, 24, a3)
      if (l < 32) xs += xr0[l];
    }
    int s = m & 7;
#pragma unroll
    for (int q = 0; q < 4; ++q) {
      int sc = (l + 64 * q) ^ s;
      uint4 o;
      o.x = pk2(acc[q * 8 + 0], acc[q * 8 + 1]);
      o.y = pk2(acc[q * 8 + 2], acc[q * 8 + 3]);
      o.z = pk2(acc[q * 8 + 4], acc[q * 8 + 5]);
      o.w = pk2(acc[q * 8 + 6], acc[q * 8 + 7]);
      *(uint4*)(Ps + m * KA + sc * 8) = o;
    }
    if (l < 32) {
      int cnt = s1 - s0; if (cnt < 1) cnt = 1;
      int c1 = (256 + (l >> 3)) ^ s, c2 = (260 + (l >> 3)) ^ s;
      Ps[m * KA + c1 * 8 + (l & 7)] = f2bf(xs);
      Ps[m * KA + c2 * 8 + (l & 7)] = f2bf(x[n * 32 + l] * (float)cnt);
    }
  }
  __syncthreads();
  // ---- phase 2: GEMM K-loop, wave w owns col block w*16..+16 ----
  int col = l & 15, sub = l >> 4;
  int sw = col & 7;
  const bfrag* Bb = (const bfrag*)Bp + w * 64 + l;
  facc ac = {0.f, 0.f, 0.f, 0.f};
#pragma unroll 4
  for (int kb = 0; kb < NKB; ++kb) {
    int sc = ((kb << 2) + sub) ^ sw;
    bfrag af = *(const bfrag*)(Ps + col * KA + sc * 8);
    ac = __builtin_amdgcn_mfma_f32_16x16x32_bf16(af, Bb[kb * 256], ac, 0, 0, 0);
  }
  float cv = convb[w * 16 + col];
#pragma unroll
  for (int j = 0; j < 4; ++j) {
    int m = sub * 4 + j, n = n0 + m;
    int cnt = starts[n + 1] - starts[n]; if (cnt < 1) cnt = 1;
    float inv = 1.f / (float)cnt;
    xhT[m * 68 + w * 16 + col] = f2bf(fmaxf(ac[j] * inv + cv, 0.f));
  }
  __syncthreads();
  // ---- phase 3: QKV, wave w owns 3 of 12 col blocks ----
  bfrag af0 = *(const bfrag*)&xhT[col * 68 + sub * 8];
  bfrag af1 = *(const bfrag*)&xhT[col * 68 + 32 + sub * 8];
  const bfrag* B2b = (const bfrag*)B2p + l;
#pragma unroll
  for (int c3 = 0; c3 < 3; ++c3) {
    int cb = w * 3 + c3;
    facc qa = {0.f, 0.f, 0.f, 0.f};
    qa = __builtin_amdgcn_mfma_f32_16x16x32_bf16(af0, B2b[cb * 64], qa, 0, 0, 0);
    qa = __builtin_amdgcn_mfma_f32_16x16x32_bf16(af1, B2b[(12 + cb) * 64], qa, 0, 0, 0);
#pragma unroll
    for (int j = 0; j < 4; ++j) {
      int n = n0 + sub * 4 + j;
      int g = n / 200, p = n - g * 200;
      int c = cb * 16 + col;
      float v = qa[j] + inb[c];
      int part = c >> 6, rem = c & 63, hh = rem >> 4, dd = rem & 15;
      float* dst = (part == 0) ? Qb : (part == 1 ? Kb : Vb);
      dst[(((size_t)g * 4 + hh) * 200 + p) * 16 + dd] = v;
    }
  }
}

// ---------------- MFMA flash attention: one block per (graph, head) ----------------
__global__ __launch_bounds__(256) void k_attn(const float* __restrict__ Qb,
    const float* __restrict__ Kb, const float* __restrict__ Vb,
    float* __restrict__ ctx) {
  __shared__ unsigned short Ks[224 * 24];
  __shared__ unsigned short Vt[16 * 232];
  __shared__ unsigned short Pl[4][16 * 40];
  int t = threadIdx.x;
  size_t base = (size_t)blockIdx.x * 3200;
  for (int idx = t; idx < 224 * 16; idx += 256) {
    int row = idx >> 4, d = idx & 15;
    float kv = (row < 200) ? Kb[base + idx] : 0.f;
    float vv = (row < 200) ? Vb[base + idx] : 0.f;
    Ks[row * 24 + d] = f2bf(kv);
    Vt[d * 232 + row] = f2bf(vv);
  }
  __syncthreads();
  int w = t >> 6, l = t & 63;
  int sub = l >> 4, col = l & 15;
  for (int qt = w; qt < 13; qt += 4) {
    bfrag qf = {0, 0, 0, 0, 0, 0, 0, 0};
    int q = qt * 16 + col;
    if (sub < 2 && q < 200) {
      const float* qp = Qb + base + q * 16 + sub * 8;
      float4 qa = *(const float4*)qp;
      float4 qb = *(const float4*)(qp + 4);
      qf[0] = (short)f2bf(qa.x); qf[1] = (short)f2bf(qa.y);
      qf[2] = (short)f2bf(qa.z); qf[3] = (short)f2bf(qa.w);
      qf[4] = (short)f2bf(qb.x); qf[5] = (short)f2bf(qb.y);
      qf[6] = (short)f2bf(qb.z); qf[7] = (short)f2bf(qb.w);
    }
    facc o = {0.f, 0.f, 0.f, 0.f};
    float srow0 = 0.f, srow1 = 0.f, srow2 = 0.f, srow3 = 0.f;
    for (int kt2 = 0; kt2 < 7; ++kt2) {
      int kt0 = kt2 * 2, kt1 = kt0 + 1;
      bfrag kf0 = {0, 0, 0, 0, 0, 0, 0, 0};
      bfrag kf1 = {0, 0, 0, 0, 0, 0, 0, 0};
      if (sub < 2) {
        kf0 = *(const bfrag*)&Ks[(kt0 * 16 + col) * 24 + sub * 8];
        kf1 = *(const bfrag*)&Ks[(kt1 * 16 + col) * 24 + sub * 8];
      }
      facc z = {0.f, 0.f, 0.f, 0.f};
      facc s0 = __builtin_amdgcn_mfma_f32_16x16x32_bf16(qf, kf0, z, 0, 0, 0);
      facc s1 = __builtin_amdgcn_mfma_f32_16x16x32_bf16(qf, kf1, z, 0, 0, 0);
      bool ok0 = (kt0 * 16 + col) < 200;
      bool ok1 = (kt1 * 16 + col) < 200;
#pragma unroll
      for (int j = 0; j < 4; ++j) {
        float e0 = ok0 ? __expf(s0[j] * 0.25f) : 0.f;
        float e1 = ok1 ? __expf(s1[j] * 0.25f) : 0.f;
        if (j == 0) { srow0 += e0 + e1; } else if (j == 1) { srow1 += e0 + e1; }
        else if (j == 2) { srow2 += e0 + e1; } else { srow3 += e0 + e1; }
        int qr = (sub << 2) + j;
        Pl[w][qr * 40 + col] = f2bf(e0);
        Pl[w][qr * 40 + 16 + col] = f2bf(e1);
      }
      bfrag pf = *(const bfrag*)&Pl[w][col * 40 + sub * 8];
      bfrag vf = *(const bfrag*)&Vt[col * 232 + kt2 * 32 + sub * 8];
      o = __builtin_amdgcn_mfma_f32_16x16x32_bf16(pf, vf, o, 0, 0, 0);
    }
#pragma unroll
    for (int off = 1; off < 16; off <<= 1) {
      srow0 += __shfl_xor(srow0, off);
      srow1 += __shfl_xor(srow1, off);
      srow2 += __shfl_xor(srow2, off);
      srow3 += __shfl_xor(srow3, off);
    }
#pragma unroll
    for (int j = 0; j < 4; ++j) {
      int qq = qt * 16 + (sub << 2) + j;
      float sr = (j == 0) ? srow0 : (j == 1) ? srow1 : (j == 2) ? srow2 : srow3;
      if (qq < 200) ctx[base + qq * 16 + col] = o[j] / sr;
    }
  }
}

// ---------------- pool + MLP head ----------------
__global__ __launch_bounds__(64) void k_head(const float* __restrict__ ctx,
    const float* __restrict__ ow, const float* __restrict__ ob,
    const float* __restrict__ w1, const float* __restrict__ b1,
    const float* __restrict__ w2, const float* __restrict__ b2,
    float* __restrict__ out) {
  __shared__ float ms[64], es[64];
  int g = blockIdx.x, t = threadIdx.x;
  int hh = t >> 4, dd = t & 15;
  const float* cb = ctx + (((size_t)g * 4 + hh) * 200) * 16 + dd;
  float s = 0.f;
  for (int p = 0; p < 200; ++p) s += cb[p * 16];
  ms[t] = s * (1.f / 200.f);
  __syncthreads();
  float e = ob[t];
  for (int j = 0; j < 64; ++j) e += ow[t * 64 + j] * ms[j];
  es[t] = e;
  __syncthreads();
  float h1 = b1[t];
  for (int j = 0; j < 64; ++j) h1 += w1[t * 64 + j] * es[j];
  h1 = fmaxf(h1, 0.f);
  float pr = h1 * w2[t];
  for (int off = 32; off >= 1; off >>= 1) pr += __shfl_xor(pr, off);
  if (t == 0) out[g] = pr + b2[0];
}

extern "C" void kernel_launch(void* const* d_in, const int* in_sizes, int n_in,
                              void* d_out, int out_size, void* d_ws, size_t ws_size,
                              hipStream_t stream) {
  (void)in_sizes; (void)n_in;
  const float* x      = (const float*)d_in[0];
  const int*   eidx   = (const int*)d_in[1];
  const float* ea     = (const float*)d_in[2];
  const float* en_w1  = (const float*)d_in[4];
  const float* en_b1  = (const float*)d_in[5];
  const float* en_w2  = (const float*)d_in[6];
  const float* en_b2  = (const float*)d_in[7];
  const float* root_w = (const float*)d_in[8];
  const float* conv_b = (const float*)d_in[9];
  const float* in_w   = (const float*)d_in[10];
  const float* in_b   = (const float*)d_in[11];
  const float* out_w  = (const float*)d_in[12];
  const float* out_b  = (const float*)d_in[13];
  const float* l1w    = (const float*)d_in[14];
  const float* l1b    = (const float*)d_in[15];
  const float* l2w    = (const float*)d_in[16];
  const float* l2b    = (const float*)d_in[17];
  float* out = (float*)d_out;

  // ---- workspace layout (bytes) ----
  char* w = (char*)d_ws;
  unsigned short* hes = (unsigned short*)w;            // 20,480,000 (dst-sorted he)
  float* Qb  = (float*)(w + 20480000);                 //  5,120,000
  float* Kb  = (float*)(w + 25600000);
  float* Vb  = (float*)(w + 30720000);
  float* ctx = (float*)(w + 35840000);                 // ends 40,960,000
  char* r3 = w + 40960000;
  unsigned short* Bp  = (unsigned short*)r3;             // 270,336
  unsigned short* B2p = (unsigned short*)(r3 + 270336);  // 24,576
  int* starts = (int*)(r3 + 270336 + 24576);             // N+1 (+pad)
  int* perm   = starts + (N_N + 4);                      // N_E
  int* srcl   = perm + N_E;                              // N_E
  int* cursor = srcl + N_E;                              // N_N
  size_t need = 40960000 + 270336 + 24576
              + (size_t)(N_N + 4) * 4 + 2 * (size_t)N_E * 4 + (size_t)N_N * 4;
  if (ws_size < need || out_size < 100) return;

  hipMemsetAsync(cursor, 0, N_N * 4, stream);
  k_pack<<<580, 256, 0, stream>>>(en_w2, en_b2, root_w, in_w, Bp, B2p);
  k_hist<<<N_E / 256, 256, 0, stream>>>(eidx, cursor);
  k_scan<<<1, 1024, 0, stream>>>(cursor, starts);
  k_scatter<<<N_E / 256, 256, 0, stream>>>(eidx, cursor, perm, srcl);
  k_mlp1<<<5000, 256, 0, stream>>>(ea, en_w1, en_b1, perm, hes);
  k_fused<<<1250, 256, 0, stream>>>(x, hes, starts, srcl, Bp, B2p,
                                    conv_b, in_b, Qb, Kb, Vb);
  k_attn<<<400, 256, 0, stream>>>(Qb, Kb, Vb, ctx);
  k_head<<<100, 64, 0, stream>>>(ctx, out_w, out_b, l1w, l1b, l2w, l2b, out);
}